// Round 3
// baseline (764.177 us; speedup 1.0000x reference)
//
#include <hip/hip_runtime.h>
#include <hip/hip_cooperative_groups.h>
#include <math.h>

namespace cg = cooperative_groups;

#define Bg 256
#define Nn 4096
#define Ee 65536
#define Kk (Nn * 3)   // 12288

__device__ __forceinline__ unsigned bf16r(float v) {   // fp32 -> bf16 bits, RNE
    unsigned b = __float_as_uint(v);
    return (b + 0x7fffu + ((b >> 16) & 1u)) >> 16;
}

// One cooperative kernel, 1024 blocks x 256 threads, 4 blocks/CU co-resident.
// Phases separated by grid.sync() instead of kernel boundaries (each boundary
// costs launch ramp/drain + cross-XCD L2 writeback/invalidate on 8-XCD gfx950).
__global__ __launch_bounds__(256, 4) void k_fused(
    const float* __restrict__ x,
    const float* __restrict__ W1,
    const float* __restrict__ b1,
    const float* __restrict__ Wfc,
    const float* __restrict__ bfc,
    const int*   __restrict__ src,
    const int*   __restrict__ dst,
    uint2* __restrict__ xsb,
    int*   __restrict__ deg_out,
    int*   __restrict__ cursor,
    int*   __restrict__ csr,
    float* __restrict__ partial,
    float* __restrict__ out)
{
    cg::grid_group grid = cg::this_grid();
    __shared__ float4 tile4[16][49];    // P2 staging: 16 batch rows x 192 floats (+pad)
    __shared__ float  cs[64];           // P2: rsqrt(deg_out)
    __shared__ float4 sW14[64];         // P3: W1 columns + bias
    __shared__ float  sWfc[16][64];     // P3: Wfc rows for this block's 16 nodes
    __shared__ float  red[4][64];       // P3: cross-wave reduce
    __shared__ float  rbuf[256];        // P4: block reduce

    const int t256 = threadIdx.x;
    const int bid  = blockIdx.x;
    const int gtid = bid * 256 + t256;

    // ---------------- P0: zero counters (replaces hipMemsetAsync) ----------------
    if (gtid < Nn) deg_out[gtid] = 0;
    else if (gtid < 2 * Nn) cursor[gtid - Nn] = 0;
    __threadfence();
    grid.sync();

    // ---------------- P1: edge prep: deg_out histogram + capacity-64 CSR ----------------
    if (gtid < Ee) {
        int s = src[gtid], d = dst[gtid];
        atomicAdd(&deg_out[s], 1);
        int ofs = atomicAdd(&cursor[d], 1) & 63;   // capacity 64 (max in-deg ~35)
        csr[(d << 6) + ofs] = s;
    }
    __threadfence();
    grid.sync();

    // ---------------- P2: scaled transpose -> bf16 slabs ----------------
    // 1024 tiles: 64 node-tiles x 4 slabs x 4 batch-chunks of 16 rows.
    {
        const int ni = bid >> 4;           // node tile [0,64)
        const int bq = (bid >> 2) & 3;     // slab
        const int ci = bid & 3;            // batch chunk within slab
        const int n0 = ni * 64;
        if (t256 < 64) cs[t256] = rsqrtf(fmaxf((float)deg_out[n0 + t256], 1.0f));
        const float* xb = x + (size_t)(bq * 64 + ci * 16) * Kk + (size_t)n0 * 3;
#pragma unroll
        for (int i = 0; i < 3; i++) {      // 16 rows x 48 float4 = 768 loads
            int idx = i * 256 + t256;
            int r = idx / 48, j = idx - r * 48;
            tile4[r][j] = ((const float4*)(xb + (size_t)r * Kk))[j];
        }
        __syncthreads();
        const float* tile = (const float*)tile4;   // [16][196]
        uint2* outp = xsb + ((size_t)bq * Nn + n0) * 64 + ci * 16;
#pragma unroll
        for (int i = 0; i < 4; i++) {      // 64 nodes x 16 lanes
            int idx = i * 256 + t256;
            int nn = idx >> 4, bl = idx & 15;
            float c = cs[nn];
            float f0 = tile[bl * 196 + nn * 3 + 0] * c;
            float f1 = tile[bl * 196 + nn * 3 + 1] * c;
            float f2 = tile[bl * 196 + nn * 3 + 2] * c;
            uint2 u;
            u.x = bf16r(f0) | (bf16r(f1) << 16);
            u.y = bf16r(f2);
            outp[(size_t)nn * 64 + bl] = u;
        }
    }
    __threadfence();
    grid.sync();

    // ---------------- P3: fused gather + (3->64) matmul + relu + Wfc dot ----------------
    // block = (g, bq): 16 nodes x 1 slab; wave w handles nodes g*16 + w*4 + {0..3};
    // lane = batch element. v0's proven skeleton: one coalesced 256 B edge-list load
    // per node, sources broadcast via __shfl, weights LDS-staged (broadcast reads).
    {
        const int t  = t256 & 63;
        const int w  = t256 >> 6;
        const int bq = bid & 3;            // blockIdx%8 -> XCD, so XCD i serves slab i&3
        const int g  = bid >> 2;           // node group [0,256)
        if (t256 < 64) sW14[t256] = make_float4(W1[t256], W1[64 + t256], W1[128 + t256], b1[t256]);
        ((float4*)sWfc)[t256] = ((const float4*)(Wfc + ((size_t)g << 10)))[t256];
        __syncthreads();
        const uint2* __restrict__ slab = xsb + (size_t)bq * (Nn * 64);
        float part = 0.f;
        for (int j = 0; j < 4; j++) {
            const int n = (g << 4) + (w << 2) + j;
            int myedge = csr[(n << 6) + t];        // whole edge list in one wave load
            int deg = cursor[n]; if (deg > 64) deg = 64;
            float a0 = 0.f, a1 = 0.f, a2 = 0.f;
            float c0 = 0.f, c1 = 0.f, c2 = 0.f;
            int i = 0;
            for (; i + 4 <= deg; i += 4) {
                int s0 = __shfl(myedge, i);
                int s1 = __shfl(myedge, i + 1);
                int s2 = __shfl(myedge, i + 2);
                int s3 = __shfl(myedge, i + 3);
                uint2 u0 = slab[(s0 << 6) + t];
                uint2 u1 = slab[(s1 << 6) + t];
                uint2 u2 = slab[(s2 << 6) + t];
                uint2 u3 = slab[(s3 << 6) + t];
                a0 += __uint_as_float(u0.x << 16); a1 += __uint_as_float(u0.x & 0xffff0000u); a2 += __uint_as_float(u0.y << 16);
                c0 += __uint_as_float(u1.x << 16); c1 += __uint_as_float(u1.x & 0xffff0000u); c2 += __uint_as_float(u1.y << 16);
                a0 += __uint_as_float(u2.x << 16); a1 += __uint_as_float(u2.x & 0xffff0000u); a2 += __uint_as_float(u2.y << 16);
                c0 += __uint_as_float(u3.x << 16); c1 += __uint_as_float(u3.x & 0xffff0000u); c2 += __uint_as_float(u3.y << 16);
            }
            for (; i < deg; i++) {
                int s = __shfl(myedge, i);
                uint2 u = slab[(s << 6) + t];
                a0 += __uint_as_float(u.x << 16);
                a1 += __uint_as_float(u.x & 0xffff0000u);
                a2 += __uint_as_float(u.y << 16);
            }
            a0 += c0; a1 += c1; a2 += c2;
            float cd = rsqrtf(fmaxf((float)deg, 1.0f));
            a0 *= cd; a1 *= cd; a2 *= cd;
            const float* wrow = &sWfc[(w << 2) + j][0];
            float p2 = 0.f;
#pragma unroll 8
            for (int f = 0; f < 64; f++) {
                float4 wv = sW14[f];
                float h = fmaf(a0, wv.x, fmaf(a1, wv.y, fmaf(a2, wv.z, wv.w)));
                p2 = fmaf(fmaxf(h, 0.f), wrow[f], p2);
            }
            part += p2;
        }
        red[w][t] = part;
        __syncthreads();
        if (w == 0) {
            float tot = (red[0][t] + red[1][t]) + (red[2][t] + red[3][t]);
            partial[(g << 8) + (bq << 6) + t] = tot;   // coalesced 256 B per block
        }
    }
    __threadfence();
    grid.sync();

    // ---------------- P4: reduce over 256 node groups + sigmoid ----------------
    // one block per output element s = bq*64 + t  (256 parallel blocks, no atomics)
    if (bid < 256) {
        rbuf[t256] = partial[(t256 << 8) + bid];
        __syncthreads();
        if (t256 < 128) rbuf[t256] += rbuf[t256 + 128];
        __syncthreads();
        if (t256 < 64) {
            float s = rbuf[t256] + rbuf[t256 + 64];
            s += __shfl_down(s, 32);
            s += __shfl_down(s, 16);
            s += __shfl_down(s, 8);
            s += __shfl_down(s, 4);
            s += __shfl_down(s, 2);
            s += __shfl_down(s, 1);
            if (t256 == 0) out[bid] = 1.0f / (1.0f + expf(-(s + bfc[0])));
        }
    }
}

extern "C" void kernel_launch(void* const* d_in, const int* in_sizes, int n_in,
                              void* d_out, int out_size, void* d_ws, size_t ws_size,
                              hipStream_t stream) {
    const float* x   = (const float*)d_in[0];
    const float* W1  = (const float*)d_in[1];
    const float* b1  = (const float*)d_in[2];
    const float* Wfc = (const float*)d_in[3];
    const float* bfc = (const float*)d_in[4];
    const int*   src = (const int*)d_in[5];
    const int*   dst = (const int*)d_in[6];
    float* out = (float*)d_out;

    char* ws = (char*)d_ws;
    uint2* xsb = (uint2*)ws;                       // 4 slabs x 2 MB = 8,388,608 B
    const size_t Z = (size_t)4 * Nn * 64 * 8;
    int*   deg_out = (int*)(ws + Z);               // 16 KB
    int*   cursor  = (int*)(ws + Z + 16384);       // 16 KB
    int*   csr     = (int*)(ws + Z + 32768);       // 4096*64 ints = 1 MB
    float* partial = (float*)(ws + Z + 32768 + 1048576);   // 256 KB

    void* args[] = { (void*)&x, (void*)&W1, (void*)&b1, (void*)&Wfc, (void*)&bfc,
                     (void*)&src, (void*)&dst, (void*)&xsb, (void*)&deg_out,
                     (void*)&cursor, (void*)&csr, (void*)&partial, (void*)&out };
    hipLaunchCooperativeKernel((void*)k_fused, dim3(1024), dim3(256), args, 0, stream);
}

// Round 4
// 345.231 us; speedup vs baseline: 2.2135x; 2.2135x over previous
//
#include <hip/hip_runtime.h>
#include <math.h>

#define Bg 256
#define Nn 4096
#define Ee 65536
#define Kk (Nn * 3)   // 12288

__device__ __forceinline__ unsigned bf16r(float v) {   // fp32 -> bf16 bits, RNE
    unsigned b = __float_as_uint(v);
    return (b + 0x7fffu + ((b >> 16) & 1u)) >> 16;
}

// ---------------- fused edge-prep + raw-bf16 transpose (independent halves) ----------------
// bid <  256 : edge prep — deg_out histogram + capacity-64 CSR by dst
// bid >= 256 : transpose x -> bf16-packed slabs, NO c_src scaling (applied at gather)
__global__ __launch_bounds__(256) void k_pt(const float* __restrict__ x,
                                            const int* __restrict__ src,
                                            const int* __restrict__ dst,
                                            int* __restrict__ deg_out,
                                            int* __restrict__ cursor,
                                            int* __restrict__ csr,
                                            uint2* __restrict__ xsb) {
    __shared__ float4 tile4[64][49];           // row stride 196 floats
    const int t = threadIdx.x;
    const int bid = blockIdx.x;
    if (bid < 256) {                           // ---- prep half ----
        int e = bid * 256 + t;
        int s = src[e], d = dst[e];
        atomicAdd(&deg_out[s], 1);
        int ofs = atomicAdd(&cursor[d], 1) & 63;   // capacity 64 (max in-deg ~35 << 64)
        csr[(d << 6) + ofs] = s;
        return;
    }
    const int bt = bid - 256;                  // ---- transpose half ----
    const int ni = bt & 63, bq = bt >> 6;
    const int n0 = ni * 64;
    const float* xb = x + (size_t)bq * 64 * Kk + (size_t)n0 * 3;
#pragma unroll
    for (int i = 0; i < 12; i++) {
        int idx = i * 256 + t;
        int bi = idx / 48, j = idx - bi * 48;
        tile4[bi][j] = ((const float4*)(xb + (size_t)bi * Kk))[j];
    }
    __syncthreads();
    const float* tile = (const float*)tile4;   // [64][196]
    uint2* outp = xsb + ((size_t)bq * Nn + n0) * 64;
#pragma unroll
    for (int i = 0; i < 16; i++) {
        int idx = i * 256 + t;
        int nn = idx >> 6, bl = idx & 63;      // per wave: nn fixed, bl = lane
        float f0 = tile[bl * 196 + nn * 3 + 0];
        float f1 = tile[bl * 196 + nn * 3 + 1];
        float f2 = tile[bl * 196 + nn * 3 + 2];
        uint2 u;
        u.x = bf16r(f0) | (bf16r(f1) << 16);
        u.y = bf16r(f2);
        outp[(size_t)nn * 64 + bl] = u;
    }
}

// ---------------- fused gather + (3->64) matmul + relu + Wfc dot + full reduce ----------------
// v0's proven skeleton: 4 waves/block, ONE node per wave; lane = batch element.
// Edge list + its c_src loaded once per wave, broadcast via __shfl; unpack-fma applies c_src.
// Tail: per-block atomicAdd into out_acc (256 addrs), last block applies sigmoid.
__global__ __launch_bounds__(256) void k_main(const uint2* __restrict__ xsb,
                                              const float* __restrict__ W1,
                                              const float* __restrict__ b1,
                                              const float* __restrict__ Wfc,
                                              const float* __restrict__ bfc,
                                              const int* __restrict__ deg_out,
                                              const int* __restrict__ cursor,
                                              const int* __restrict__ csr,
                                              float* __restrict__ out_acc,
                                              int* __restrict__ done,
                                              float* __restrict__ out) {
    __shared__ float4 sW14[64];
    __shared__ float sWfc[4][64];
    __shared__ float red[4][64];
    __shared__ int lastblk;
    const int t = threadIdx.x & 63;
    const int w = threadIdx.x >> 6;
    const int bq = blockIdx.x & 3;      // slab; XCD i (bid%8) sees bq=i&3 -> L2-resident slab
    const int g  = blockIdx.x >> 2;     // node group [0,1024)
    const int n  = g * 4 + w;
    if (w == 0) sW14[t] = make_float4(W1[t], W1[64 + t], W1[128 + t], b1[t]);
    sWfc[w][t] = Wfc[n * 64 + t];
    __syncthreads();

    const uint2* __restrict__ slab = xsb + (size_t)bq * (Nn * 64);
    int e = csr[(n << 6) + t] & (Nn - 1);   // mask: slots >= deg hold poison, keep in-bounds
    float cs_t = rsqrtf(fmaxf((float)deg_out[e], 1.0f));   // c_src for lane's edge
    int deg = cursor[n]; if (deg > 64) deg = 64;
    float a0 = 0.f, a1 = 0.f, a2 = 0.f;
    float c0 = 0.f, c1 = 0.f, c2 = 0.f;
    int i = 0;
    for (; i + 4 <= deg; i += 4) {
        int s0 = __shfl(e, i);
        int s1 = __shfl(e, i + 1);
        int s2 = __shfl(e, i + 2);
        int s3 = __shfl(e, i + 3);
        float q0 = __shfl(cs_t, i);
        float q1 = __shfl(cs_t, i + 1);
        float q2 = __shfl(cs_t, i + 2);
        float q3 = __shfl(cs_t, i + 3);
        uint2 u0 = slab[(s0 << 6) + t];
        uint2 u1 = slab[(s1 << 6) + t];
        uint2 u2 = slab[(s2 << 6) + t];
        uint2 u3 = slab[(s3 << 6) + t];
        a0 = fmaf(q0, __uint_as_float(u0.x << 16), a0);
        a1 = fmaf(q0, __uint_as_float(u0.x & 0xffff0000u), a1);
        a2 = fmaf(q0, __uint_as_float(u0.y << 16), a2);
        c0 = fmaf(q1, __uint_as_float(u1.x << 16), c0);
        c1 = fmaf(q1, __uint_as_float(u1.x & 0xffff0000u), c1);
        c2 = fmaf(q1, __uint_as_float(u1.y << 16), c2);
        a0 = fmaf(q2, __uint_as_float(u2.x << 16), a0);
        a1 = fmaf(q2, __uint_as_float(u2.x & 0xffff0000u), a1);
        a2 = fmaf(q2, __uint_as_float(u2.y << 16), a2);
        c0 = fmaf(q3, __uint_as_float(u3.x << 16), c0);
        c1 = fmaf(q3, __uint_as_float(u3.x & 0xffff0000u), c1);
        c2 = fmaf(q3, __uint_as_float(u3.y << 16), c2);
    }
    for (; i < deg; i++) {
        int s = __shfl(e, i);
        float q = __shfl(cs_t, i);
        uint2 u = slab[(s << 6) + t];
        a0 = fmaf(q, __uint_as_float(u.x << 16), a0);
        a1 = fmaf(q, __uint_as_float(u.x & 0xffff0000u), a1);
        a2 = fmaf(q, __uint_as_float(u.y << 16), a2);
    }
    a0 += c0; a1 += c1; a2 += c2;
    float cd = rsqrtf(fmaxf((float)deg, 1.0f));
    a0 *= cd; a1 *= cd; a2 *= cd;

    float part = 0.f;
#pragma unroll 8
    for (int f = 0; f < 64; f++) {
        float4 wv = sW14[f];
        float h = fmaf(a0, wv.x, fmaf(a1, wv.y, fmaf(a2, wv.z, wv.w)));
        part = fmaf(fmaxf(h, 0.f), sWfc[w][f], part);
    }
    red[w][t] = part;
    __syncthreads();
    if (w == 0) {
        float tot = (red[0][t] + red[1][t]) + (red[2][t] + red[3][t]);
        atomicAdd(&out_acc[(bq << 6) + t], tot);
    }
    // ---- last-block epilogue (canonical threadfence-reduction pattern) ----
    __threadfence();
    __syncthreads();
    if (threadIdx.x == 0) lastblk = (atomicAdd(done, 1) == (int)gridDim.x - 1);
    __syncthreads();
    if (lastblk) {
        float v = atomicAdd(&out_acc[threadIdx.x], 0.0f) + bfc[0];   // coherent read
        out[threadIdx.x] = 1.0f / (1.0f + expf(-v));
    }
}

extern "C" void kernel_launch(void* const* d_in, const int* in_sizes, int n_in,
                              void* d_out, int out_size, void* d_ws, size_t ws_size,
                              hipStream_t stream) {
    const float* x   = (const float*)d_in[0];
    const float* W1  = (const float*)d_in[1];
    const float* b1  = (const float*)d_in[2];
    const float* Wfc = (const float*)d_in[3];
    const float* bfc = (const float*)d_in[4];
    const int*   src = (const int*)d_in[5];
    const int*   dst = (const int*)d_in[6];
    float* out = (float*)d_out;

    char* ws = (char*)d_ws;
    uint2* xsb = (uint2*)ws;                       // 4 slabs x 2 MB = 8,388,608 B
    const size_t Z = (size_t)4 * Nn * 64 * 8;
    int*   deg_out = (int*)(ws + Z);               // 16 KB (zeroed)
    int*   cursor  = (int*)(ws + Z + 16384);       // 16 KB (zeroed)
    float* out_acc = (float*)(ws + Z + 32768);     // 1 KB  (zeroed)
    int*   done    = (int*)(ws + Z + 33792);       // 4 B   (zeroed)
    int*   csr     = (int*)(ws + Z + 34048);       // 4096*64 ints = 1 MB

    hipMemsetAsync(ws + Z, 0, 34048, stream);
    k_pt<<<512, 256, 0, stream>>>(x, src, dst, deg_out, cursor, csr, xsb);
    k_main<<<1024 * 4, 256, 0, stream>>>(xsb, W1, b1, Wfc, bfc, deg_out, cursor, csr,
                                         out_acc, done, out);
}

// Round 5
// 109.968 us; speedup vs baseline: 6.9491x; 3.1394x over previous
//
#include <hip/hip_runtime.h>
#include <math.h>

#define Bg 256
#define Nn 4096
#define Ee 65536
#define Kk (Nn * 3)   // 12288

__device__ __forceinline__ unsigned bf16r(float v) {   // fp32 -> bf16 bits, RNE
    unsigned b = __float_as_uint(v);
    return (b + 0x7fffu + ((b >> 16) & 1u)) >> 16;
}

// ---------------- fused edge-prep + raw-bf16 transpose (independent halves) ----------------
// bid <  256 : edge prep — deg_out histogram + capacity-64 CSR by dst
// bid >= 256 : transpose x -> bf16-packed slabs (no c_src scaling; applied at gather)
__global__ __launch_bounds__(256) void k_pt(const float* __restrict__ x,
                                            const int* __restrict__ src,
                                            const int* __restrict__ dst,
                                            int* __restrict__ deg_out,
                                            int* __restrict__ cursor,
                                            int* __restrict__ csr,
                                            uint2* __restrict__ xsb) {
    __shared__ float4 tile4[64][49];           // row stride 196 floats
    const int t = threadIdx.x;
    const int bid = blockIdx.x;
    if (bid < 256) {                           // ---- prep half ----
        int e = bid * 256 + t;
        int s = src[e], d = dst[e];
        atomicAdd(&deg_out[s], 1);
        int ofs = atomicAdd(&cursor[d], 1) & 63;   // capacity 64 (max in-deg ~35 << 64)
        csr[(d << 6) + ofs] = s;
        return;
    }
    const int bt = bid - 256;                  // ---- transpose half ----
    const int ni = bt & 63, bq = bt >> 6;
    const int n0 = ni * 64;
    const float* xb = x + (size_t)bq * 64 * Kk + (size_t)n0 * 3;
#pragma unroll
    for (int i = 0; i < 12; i++) {
        int idx = i * 256 + t;
        int bi = idx / 48, j = idx - bi * 48;
        tile4[bi][j] = ((const float4*)(xb + (size_t)bi * Kk))[j];
    }
    __syncthreads();
    const float* tile = (const float*)tile4;   // [64][196]
    uint2* outp = xsb + ((size_t)bq * Nn + n0) * 64;
#pragma unroll
    for (int i = 0; i < 16; i++) {
        int idx = i * 256 + t;
        int nn = idx >> 6, bl = idx & 63;      // per wave: nn fixed, bl = lane
        float f0 = tile[bl * 196 + nn * 3 + 0];
        float f1 = tile[bl * 196 + nn * 3 + 1];
        float f2 = tile[bl * 196 + nn * 3 + 2];
        uint2 u;
        u.x = bf16r(f0) | (bf16r(f1) << 16);
        u.y = bf16r(f2);
        outp[(size_t)nn * 64 + bl] = u;
    }
}

// ---------------- fused gather + (3->64) matmul + relu + Wfc dot ----------------
// v0's proven skeleton: 4 waves/block, ONE node per wave; lane = batch element.
// Edge list + its c_src loaded once per wave, broadcast via __shfl.
// NO atomics, NO fence: plain coalesced partial store (the v4 tail was the 230 us stall).
__global__ __launch_bounds__(256) void k_main(const uint2* __restrict__ xsb,
                                              const float* __restrict__ W1,
                                              const float* __restrict__ b1,
                                              const float* __restrict__ Wfc,
                                              const int* __restrict__ deg_out,
                                              const int* __restrict__ cursor,
                                              const int* __restrict__ csr,
                                              float* __restrict__ partial) {
    __shared__ float4 sW14[64];
    __shared__ float sWfc[4][64];
    __shared__ float red[4][64];
    const int t = threadIdx.x & 63;
    const int w = threadIdx.x >> 6;
    const int bq = blockIdx.x & 3;      // slab; XCD i (bid%8) sees bq=i&3 -> L2-resident slab
    const int g  = blockIdx.x >> 2;     // node group [0,1024)
    const int n  = g * 4 + w;
    if (w == 0) sW14[t] = make_float4(W1[t], W1[64 + t], W1[128 + t], b1[t]);
    sWfc[w][t] = Wfc[n * 64 + t];
    __syncthreads();

    const uint2* __restrict__ slab = xsb + (size_t)bq * (Nn * 64);
    int e = csr[(n << 6) + t] & (Nn - 1);   // mask: slots >= deg hold poison, keep in-bounds
    float cs_t = rsqrtf(fmaxf((float)deg_out[e], 1.0f));   // c_src for lane's edge
    int deg = cursor[n]; if (deg > 64) deg = 64;
    float a0 = 0.f, a1 = 0.f, a2 = 0.f;
    float c0 = 0.f, c1 = 0.f, c2 = 0.f;
    int i = 0;
    for (; i + 4 <= deg; i += 4) {
        int s0 = __shfl(e, i);
        int s1 = __shfl(e, i + 1);
        int s2 = __shfl(e, i + 2);
        int s3 = __shfl(e, i + 3);
        float q0 = __shfl(cs_t, i);
        float q1 = __shfl(cs_t, i + 1);
        float q2 = __shfl(cs_t, i + 2);
        float q3 = __shfl(cs_t, i + 3);
        uint2 u0 = slab[(s0 << 6) + t];
        uint2 u1 = slab[(s1 << 6) + t];
        uint2 u2 = slab[(s2 << 6) + t];
        uint2 u3 = slab[(s3 << 6) + t];
        a0 = fmaf(q0, __uint_as_float(u0.x << 16), a0);
        a1 = fmaf(q0, __uint_as_float(u0.x & 0xffff0000u), a1);
        a2 = fmaf(q0, __uint_as_float(u0.y << 16), a2);
        c0 = fmaf(q1, __uint_as_float(u1.x << 16), c0);
        c1 = fmaf(q1, __uint_as_float(u1.x & 0xffff0000u), c1);
        c2 = fmaf(q1, __uint_as_float(u1.y << 16), c2);
        a0 = fmaf(q2, __uint_as_float(u2.x << 16), a0);
        a1 = fmaf(q2, __uint_as_float(u2.x & 0xffff0000u), a1);
        a2 = fmaf(q2, __uint_as_float(u2.y << 16), a2);
        c0 = fmaf(q3, __uint_as_float(u3.x << 16), c0);
        c1 = fmaf(q3, __uint_as_float(u3.x & 0xffff0000u), c1);
        c2 = fmaf(q3, __uint_as_float(u3.y << 16), c2);
    }
    for (; i < deg; i++) {
        int s = __shfl(e, i);
        float q = __shfl(cs_t, i);
        uint2 u = slab[(s << 6) + t];
        a0 = fmaf(q, __uint_as_float(u.x << 16), a0);
        a1 = fmaf(q, __uint_as_float(u.x & 0xffff0000u), a1);
        a2 = fmaf(q, __uint_as_float(u.y << 16), a2);
    }
    a0 += c0; a1 += c1; a2 += c2;
    float cd = rsqrtf(fmaxf((float)deg, 1.0f));
    a0 *= cd; a1 *= cd; a2 *= cd;

    float part = 0.f;
#pragma unroll 8
    for (int f = 0; f < 64; f++) {
        float4 wv = sW14[f];
        float h = fmaf(a0, wv.x, fmaf(a1, wv.y, fmaf(a2, wv.z, wv.w)));
        part = fmaf(fmaxf(h, 0.f), sWfc[w][f], part);
    }
    red[w][t] = part;
    __syncthreads();
    if (w == 0) {
        float tot = (red[0][t] + red[1][t]) + (red[2][t] + red[3][t]);
        partial[(g << 8) + (bq << 6) + t] = tot;   // coalesced 256 B per block
    }
}

// ---------------- tail: coalesced reduce over 1024 groups + last-block sigmoid ----------------
// 64 blocks x 16 groups each; one atomicAdd round (64 per address); fence runs 64x only.
__global__ __launch_bounds__(256) void k_tail(const float* __restrict__ partial,
                                              const float* __restrict__ bfc,
                                              float* __restrict__ out_acc,
                                              int* __restrict__ done,
                                              float* __restrict__ out) {
    __shared__ int lastblk;
    const int t = threadIdx.x;
    const int g0 = blockIdx.x * 16;
    float s = 0.f;
#pragma unroll
    for (int g = 0; g < 16; g++) s += partial[((g0 + g) << 8) + t];   // coalesced
    atomicAdd(&out_acc[t], s);
    __threadfence();
    __syncthreads();
    if (t == 0) lastblk = (atomicAdd(done, 1) == (int)gridDim.x - 1);
    __syncthreads();
    if (lastblk) {
        float v = atomicAdd(&out_acc[t], 0.0f) + bfc[0];   // coherent read
        out[t] = 1.0f / (1.0f + expf(-v));
    }
}

extern "C" void kernel_launch(void* const* d_in, const int* in_sizes, int n_in,
                              void* d_out, int out_size, void* d_ws, size_t ws_size,
                              hipStream_t stream) {
    const float* x   = (const float*)d_in[0];
    const float* W1  = (const float*)d_in[1];
    const float* b1  = (const float*)d_in[2];
    const float* Wfc = (const float*)d_in[3];
    const float* bfc = (const float*)d_in[4];
    const int*   src = (const int*)d_in[5];
    const int*   dst = (const int*)d_in[6];
    float* out = (float*)d_out;

    char* ws = (char*)d_ws;
    uint2* xsb = (uint2*)ws;                       // 4 slabs x 2 MB = 8,388,608 B
    const size_t Z = (size_t)4 * Nn * 64 * 8;
    int*   deg_out = (int*)(ws + Z);               // 16 KB (zeroed)
    int*   cursor  = (int*)(ws + Z + 16384);       // 16 KB (zeroed)
    float* out_acc = (float*)(ws + Z + 32768);     // 1 KB  (zeroed)
    int*   done    = (int*)(ws + Z + 33792);       // 4 B   (zeroed)
    int*   csr     = (int*)(ws + Z + 34048);       // 4096*64 ints = 1 MB
    float* partial = (float*)(ws + Z + 34048 + 1048576);   // 1 MB

    hipMemsetAsync(ws + Z, 0, 34048, stream);
    k_pt<<<512, 256, 0, stream>>>(x, src, dst, deg_out, cursor, csr, xsb);
    k_main<<<1024 * 4, 256, 0, stream>>>(xsb, W1, b1, Wfc, deg_out, cursor, csr, partial);
    k_tail<<<64, 256, 0, stream>>>(partial, bfc, out_acc, done, out);
}

// Round 6
// 105.534 us; speedup vs baseline: 7.2411x; 1.0420x over previous
//
#include <hip/hip_runtime.h>
#include <math.h>

#define Bg 256
#define Nn 4096
#define Ee 65536
#define Kk (Nn * 3)   // 12288

__device__ __forceinline__ unsigned bf16r(float v) {   // fp32 -> bf16 bits, RNE
    unsigned b = __float_as_uint(v);
    return (b + 0x7fffu + ((b >> 16) & 1u)) >> 16;
}

// ---------------- fused edge-prep + raw-bf16 transpose (independent halves) ----------------
// bid <  256 : edge prep — deg_out histogram + capacity-64 CSR by dst
// bid >= 256 : transpose x -> bf16-packed superslabs of 128 batches
//              xsb[bq][n][bl] (bq in [0,2), bl in [0,128)), uint2 per (n,bl)
__global__ __launch_bounds__(256) void k_pt(const float* __restrict__ x,
                                            const int* __restrict__ src,
                                            const int* __restrict__ dst,
                                            int* __restrict__ deg_out,
                                            int* __restrict__ cursor,
                                            int* __restrict__ csr,
                                            uint2* __restrict__ xsb) {
    __shared__ float4 tile4[64][49];           // row stride 196 floats
    const int t = threadIdx.x;
    const int bid = blockIdx.x;
    if (bid < 256) {                           // ---- prep half ----
        int e = bid * 256 + t;
        int s = src[e], d = dst[e];
        atomicAdd(&deg_out[s], 1);
        int ofs = atomicAdd(&cursor[d], 1) & 63;   // capacity 64 (max in-deg ~35 << 64)
        csr[(d << 6) + ofs] = s;
        return;
    }
    const int bt = bid - 256;                  // ---- transpose half ----
    const int ni = bt & 63, bc = bt >> 6;      // node tile, batch chunk of 64
    const int n0 = ni * 64;
    const float* xb = x + (size_t)bc * 64 * Kk + (size_t)n0 * 3;
#pragma unroll
    for (int i = 0; i < 12; i++) {
        int idx = i * 256 + t;
        int bi = idx / 48, j = idx - bi * 48;
        tile4[bi][j] = ((const float4*)(xb + (size_t)bi * Kk))[j];
    }
    __syncthreads();
    const float* tile = (const float*)tile4;   // [64][196]
    // batch chunk bc -> superslab bc>>1, half (bc&1)*64
    uint2* outp = xsb + ((size_t)(bc >> 1) * Nn + n0) * 128 + (bc & 1) * 64;
#pragma unroll
    for (int i = 0; i < 16; i++) {
        int idx = i * 256 + t;
        int nn = idx >> 6, bl = idx & 63;      // per wave: nn fixed, bl = lane
        float f0 = tile[bl * 196 + nn * 3 + 0];
        float f1 = tile[bl * 196 + nn * 3 + 1];
        float f2 = tile[bl * 196 + nn * 3 + 2];
        uint2 u;
        u.x = bf16r(f0) | (bf16r(f1) << 16);
        u.y = bf16r(f2);
        outp[(size_t)nn * 128 + bl] = u;
    }
}

// ---------------- fused gather + (3->64) matmul + relu + Wfc dot ----------------
// 4 waves/block, ONE node per wave, TWO batch elements per lane (dwordx4 gather).
// Edge walk is wave-UNIFORM (readfirstlane n): edge ids / deg / cs ride the scalar
// pipe — zero ds_bpermute, zero per-edge VALU address math.
__global__ __launch_bounds__(256) void k_main(const uint2* __restrict__ xsb,
                                              const float* __restrict__ W1,
                                              const float* __restrict__ b1,
                                              const float* __restrict__ Wfc,
                                              const int* __restrict__ deg_out,
                                              const int* __restrict__ cursor,
                                              const int* __restrict__ csr,
                                              float* __restrict__ partial) {
    __shared__ float4 sW14[64];
    __shared__ float sWfc[4][64];
    __shared__ float2 red[4][64];
    const int t = threadIdx.x & 63;
    const int w = threadIdx.x >> 6;
    const int bq = blockIdx.x & 1;      // superslab; XCD i (bid%8) sees bq=i&1 -> L2-resident
    const int g  = blockIdx.x >> 1;     // node group [0,1024)
    const int n  = __builtin_amdgcn_readfirstlane(g * 4 + w);   // provably wave-uniform
    if (w == 0) sW14[t] = make_float4(W1[t], W1[64 + t], W1[128 + t], b1[t]);
    sWfc[w][t] = Wfc[n * 64 + t];
    __syncthreads();

    // lane t covers batches (bq*128 + 2t, +2t+1): one uint4 = 16 B per edge
    const uint4* __restrict__ slab = (const uint4*)xsb + (size_t)bq * (Nn * 64);
    const int* __restrict__ crow = csr + (n << 6);
    int deg = cursor[n]; if (deg > 64) deg = 64;            // uniform
    float a0 = 0.f, a1 = 0.f, a2 = 0.f, a3 = 0.f, a4 = 0.f, a5 = 0.f;
    float c0 = 0.f, c1 = 0.f, c2 = 0.f, c3 = 0.f, c4 = 0.f, c5 = 0.f;
    int i = 0;
#pragma unroll 2
    for (; i + 2 <= deg; i += 2) {
        int s0 = crow[i], s1 = crow[i + 1];                 // uniform -> scalar pipe
        float q0 = rsqrtf(fmaxf((float)deg_out[s0], 1.0f)); // uniform load, cheap math
        float q1 = rsqrtf(fmaxf((float)deg_out[s1], 1.0f));
        uint4 u0 = slab[(s0 << 6) + t];                     // SGPR base + lane offset
        uint4 u1 = slab[(s1 << 6) + t];
        a0 = fmaf(q0, __uint_as_float(u0.x << 16), a0);
        a1 = fmaf(q0, __uint_as_float(u0.x & 0xffff0000u), a1);
        a2 = fmaf(q0, __uint_as_float(u0.y << 16), a2);
        a3 = fmaf(q0, __uint_as_float(u0.z << 16), a3);
        a4 = fmaf(q0, __uint_as_float(u0.z & 0xffff0000u), a4);
        a5 = fmaf(q0, __uint_as_float(u0.w << 16), a5);
        c0 = fmaf(q1, __uint_as_float(u1.x << 16), c0);
        c1 = fmaf(q1, __uint_as_float(u1.x & 0xffff0000u), c1);
        c2 = fmaf(q1, __uint_as_float(u1.y << 16), c2);
        c3 = fmaf(q1, __uint_as_float(u1.z << 16), c3);
        c4 = fmaf(q1, __uint_as_float(u1.z & 0xffff0000u), c4);
        c5 = fmaf(q1, __uint_as_float(u1.w << 16), c5);
    }
    if (i < deg) {
        int s = crow[i];
        float q = rsqrtf(fmaxf((float)deg_out[s], 1.0f));
        uint4 u = slab[(s << 6) + t];
        a0 = fmaf(q, __uint_as_float(u.x << 16), a0);
        a1 = fmaf(q, __uint_as_float(u.x & 0xffff0000u), a1);
        a2 = fmaf(q, __uint_as_float(u.y << 16), a2);
        a3 = fmaf(q, __uint_as_float(u.z << 16), a3);
        a4 = fmaf(q, __uint_as_float(u.z & 0xffff0000u), a4);
        a5 = fmaf(q, __uint_as_float(u.w << 16), a5);
    }
    a0 += c0; a1 += c1; a2 += c2; a3 += c3; a4 += c4; a5 += c5;
    float cd = rsqrtf(fmaxf((float)deg, 1.0f));
    a0 *= cd; a1 *= cd; a2 *= cd; a3 *= cd; a4 *= cd; a5 *= cd;

    float pe = 0.f, po = 0.f;
#pragma unroll 8
    for (int f = 0; f < 64; f++) {
        float4 wv = sW14[f];
        float he = fmaf(a0, wv.x, fmaf(a1, wv.y, fmaf(a2, wv.z, wv.w)));
        float ho = fmaf(a3, wv.x, fmaf(a4, wv.y, fmaf(a5, wv.z, wv.w)));
        float wf = sWfc[w][f];
        pe = fmaf(fmaxf(he, 0.f), wf, pe);
        po = fmaf(fmaxf(ho, 0.f), wf, po);
    }
    red[w][t].x = pe;
    red[w][t].y = po;
    __syncthreads();
    if (w == 0) {
        float2 r0 = red[0][t], r1 = red[1][t], r2 = red[2][t], r3 = red[3][t];
        float2 tot;
        tot.x = (r0.x + r1.x) + (r2.x + r3.x);
        tot.y = (r0.y + r1.y) + (r2.y + r3.y);
        // batches bq*128+2t, +2t+1 of group g -> partial[g*256 + b] (layout as v5)
        ((float2*)partial)[(g << 7) + (bq << 6) + t] = tot;
    }
}

// ---------------- tail: coalesced reduce over 1024 groups + last-block sigmoid ----------------
// 64 blocks x 16 groups each; one atomicAdd round (64 per address); fence runs 64x only.
__global__ __launch_bounds__(256) void k_tail(const float* __restrict__ partial,
                                              const float* __restrict__ bfc,
                                              float* __restrict__ out_acc,
                                              int* __restrict__ done,
                                              float* __restrict__ out) {
    __shared__ int lastblk;
    const int t = threadIdx.x;
    const int g0 = blockIdx.x * 16;
    float s = 0.f;
#pragma unroll
    for (int g = 0; g < 16; g++) s += partial[((g0 + g) << 8) + t];   // coalesced
    atomicAdd(&out_acc[t], s);
    __threadfence();
    __syncthreads();
    if (t == 0) lastblk = (atomicAdd(done, 1) == (int)gridDim.x - 1);
    __syncthreads();
    if (lastblk) {
        float v = atomicAdd(&out_acc[t], 0.0f) + bfc[0];   // coherent read
        out[t] = 1.0f / (1.0f + expf(-v));
    }
}

extern "C" void kernel_launch(void* const* d_in, const int* in_sizes, int n_in,
                              void* d_out, int out_size, void* d_ws, size_t ws_size,
                              hipStream_t stream) {
    const float* x   = (const float*)d_in[0];
    const float* W1  = (const float*)d_in[1];
    const float* b1  = (const float*)d_in[2];
    const float* Wfc = (const float*)d_in[3];
    const float* bfc = (const float*)d_in[4];
    const int*   src = (const int*)d_in[5];
    const int*   dst = (const int*)d_in[6];
    float* out = (float*)d_out;

    char* ws = (char*)d_ws;
    uint2* xsb = (uint2*)ws;                       // 2 superslabs x 4 MB = 8,388,608 B
    const size_t Z = (size_t)2 * Nn * 128 * 8;
    int*   deg_out = (int*)(ws + Z);               // 16 KB (zeroed)
    int*   cursor  = (int*)(ws + Z + 16384);       // 16 KB (zeroed)
    float* out_acc = (float*)(ws + Z + 32768);     // 1 KB  (zeroed)
    int*   done    = (int*)(ws + Z + 33792);       // 4 B   (zeroed)
    int*   csr     = (int*)(ws + Z + 34048);       // 4096*64 ints = 1 MB
    float* partial = (float*)(ws + Z + 34048 + 1048576);   // 1 MB

    hipMemsetAsync(ws + Z, 0, 34048, stream);
    k_pt<<<512, 256, 0, stream>>>(x, src, dst, deg_out, cursor, csr, xsb);
    k_main<<<1024 * 2, 256, 0, stream>>>(xsb, W1, b1, Wfc, deg_out, cursor, csr, partial);
    k_tail<<<64, 256, 0, stream>>>(partial, bfc, out_acc, done, out);
}